// Round 6
// baseline (578.101 us; speedup 1.0000x reference)
//
#include <hip/hip_runtime.h>

#define NN 50000      // nodes
#define NE 800000     // edges
#define DHID 128
#define NGR 128       // graphs
#define DOUT 10

// ---------------- CSR build ----------------

__global__ void k_init(int* deg, int* cursor, float* gsum) {
    int i = blockIdx.x * blockDim.x + threadIdx.x;
    if (i < NN) { deg[i] = 1; cursor[i] = 0; }   // 1 = self loop
    if (i < NGR * DHID) gsum[i] = 0.f;
}

__global__ void k_count(const int* __restrict__ dst, int* __restrict__ deg) {
    int e = blockIdx.x * blockDim.x + threadIdx.x;
    if (e < NE) atomicAdd(&deg[dst[e]], 1);
}

// per-256-chunk sums of (deg-1), plus dinv
__global__ void k_scanA(const int* __restrict__ deg, float* __restrict__ dinv,
                        int* __restrict__ bsum) {
    __shared__ int sm[256];
    int t = threadIdx.x;
    int i = blockIdx.x * 256 + t;
    int d = (i < NN) ? deg[i] : 1;
    if (i < NN) dinv[i] = rsqrtf((float)d);
    sm[t] = d - 1;
    __syncthreads();
    for (int o = 128; o > 0; o >>= 1) {
        if (t < o) sm[t] += sm[t + o];
        __syncthreads();
    }
    if (t == 0) bsum[blockIdx.x] = sm[0];
}

// exclusive scan of block sums (nb <= 256) in a single block
__global__ void k_scanB(int* bsum, int nb) {
    __shared__ int sm[256];
    int t = threadIdx.x;
    int v = (t < nb) ? bsum[t] : 0;
    sm[t] = v;
    __syncthreads();
    for (int o = 1; o < 256; o <<= 1) {
        int x = (t >= o) ? sm[t - o] : 0;
        __syncthreads();
        sm[t] += x;
        __syncthreads();
    }
    if (t < nb) bsum[t] = sm[t] - v;  // exclusive
}

__global__ void k_scanC(const int* __restrict__ deg, const int* __restrict__ bsum,
                        int* __restrict__ offs) {
    __shared__ int sm[256];
    int t = threadIdx.x;
    int i = blockIdx.x * 256 + t;
    int c = (i < NN) ? deg[i] - 1 : 0;
    sm[t] = c;
    __syncthreads();
    for (int o = 1; o < 256; o <<= 1) {
        int x = (t >= o) ? sm[t - o] : 0;
        __syncthreads();
        sm[t] += x;
        __syncthreads();
    }
    if (i < NN) offs[i] = bsum[blockIdx.x] + sm[t] - c;  // exclusive within chunk
}

// packed CSR record: .x = src index, .y = f32 weight bits
__global__ void k_fill(const int* __restrict__ src, const int* __restrict__ dst,
                       const int* __restrict__ offs, int* __restrict__ cursor,
                       const float* __restrict__ dinv,
                       int2* __restrict__ csr) {
    int e = blockIdx.x * blockDim.x + threadIdx.x;
    if (e >= NE) return;
    int s = src[e], d = dst[e];
    int p = offs[d] + atomicAdd(&cursor[d], 1);
    csr[p] = make_int2(s, __float_as_int(dinv[s] * dinv[d]));
}

// ---------------- GEMM: C[NN x 128] = X[NN x 128] * W[128 x 128] ----------------
// 64-row block tile, full 128 cols. 256 threads = 16x16, 4x8 micro-tile.
__global__ __launch_bounds__(256) void k_gemm(const float* __restrict__ X,
                                              const float* __restrict__ W,
                                              float* __restrict__ C) {
    __shared__ float Xs[16][68];   // [k][row], padded
    __shared__ float Ws[16][128];  // [k][col]
    int t = threadIdx.x;
    int tx = t & 15, ty = t >> 4;
    int rowBase = blockIdx.x * 64;

    float acc[4][8];
#pragma unroll
    for (int i = 0; i < 4; i++)
#pragma unroll
        for (int j = 0; j < 8; j++) acc[i][j] = 0.f;

    for (int kk = 0; kk < 128; kk += 16) {
        {
            int r = t >> 2, q = t & 3;
            int grow = rowBase + r;
            float4 v = make_float4(0.f, 0.f, 0.f, 0.f);
            if (grow < NN)
                v = *reinterpret_cast<const float4*>(&X[grow * 128 + kk + 4 * q]);
            Xs[4 * q + 0][r] = v.x;
            Xs[4 * q + 1][r] = v.y;
            Xs[4 * q + 2][r] = v.z;
            Xs[4 * q + 3][r] = v.w;
        }
#pragma unroll
        for (int rep = 0; rep < 2; rep++) {
            int idx = t + rep * 256;
            int k = idx >> 5, c4 = idx & 31;
            *reinterpret_cast<float4*>(&Ws[k][4 * c4]) =
                *reinterpret_cast<const float4*>(&W[(kk + k) * 128 + 4 * c4]);
        }
        __syncthreads();
#pragma unroll
        for (int k = 0; k < 16; k++) {
            float4 xv = *reinterpret_cast<const float4*>(&Xs[k][4 * ty]);
            float4 w0 = *reinterpret_cast<const float4*>(&Ws[k][8 * tx]);
            float4 w1 = *reinterpret_cast<const float4*>(&Ws[k][8 * tx + 4]);
            float xa[4] = {xv.x, xv.y, xv.z, xv.w};
            float wa[8] = {w0.x, w0.y, w0.z, w0.w, w1.x, w1.y, w1.z, w1.w};
#pragma unroll
            for (int i = 0; i < 4; i++)
#pragma unroll
                for (int j = 0; j < 8; j++) acc[i][j] += xa[i] * wa[j];
        }
        __syncthreads();
    }
#pragma unroll
    for (int i = 0; i < 4; i++) {
        int grow = rowBase + 4 * ty + i;
        if (grow < NN) {
            float4 o0 = make_float4(acc[i][0], acc[i][1], acc[i][2], acc[i][3]);
            float4 o1 = make_float4(acc[i][4], acc[i][5], acc[i][6], acc[i][7]);
            *reinterpret_cast<float4*>(&C[grow * 128 + 8 * tx]) = o0;
            *reinterpret_cast<float4*>(&C[grow * 128 + 8 * tx + 4]) = o1;
        }
    }
}

// ---------------- Aggregation: out = A_norm @ feat (+bias, relu / pool) -------
// one wave per node. Half-wave float4 scheme: 32 lanes cover the 128-feature
// row (float4 each); half 0 = even edges, half 1 = odd edges. 2 edges per
// gather instruction, 8 gathers (16 edges) in flight. csr records loaded
// coalesced by lane and broadcast via shfl (no same-address vector loads).
__global__ __launch_bounds__(256) void k_agg(const float* __restrict__ feat,
                                             const int2* __restrict__ csr,
                                             const int* __restrict__ offs,
                                             const int* __restrict__ deg,
                                             const float* __restrict__ dinv,
                                             const float* __restrict__ bias,
                                             float* __restrict__ out, int relu,
                                             const int* __restrict__ batch,
                                             float* __restrict__ gsum, int do_pool) {
    int wid = threadIdx.x >> 6;
    int lane = threadIdx.x & 63;
    int node = blockIdx.x * 4 + wid;
    if (node >= NN) return;
    int half = lane >> 5;   // 0: even edges, 1: odd edges
    int hl = lane & 31;     // float4 chunk index within the row
    const float4* f4 = reinterpret_cast<const float4*>(feat);  // row stride 32

    float di = dinv[node];
    float4 a0 = make_float4(0.f, 0.f, 0.f, 0.f);
    float4 a1 = make_float4(0.f, 0.f, 0.f, 0.f);
    if (half == 0) {
        float4 v = f4[(size_t)node * 32 + hl];
        float w0 = di * di;
        a0 = make_float4(w0 * v.x, w0 * v.y, w0 * v.z, w0 * v.w);
    }
    int start = offs[node];
    int cnt = deg[node] - 1;

    int e = 0;
    for (; e + 16 <= cnt; e += 16) {
        int2 rec = csr[start + e + (lane & 15)];  // 16 records, lanes 16+ dup
#pragma unroll
        for (int j = 0; j < 8; j++) {
            int idx = 2 * j + half;
            int s = __shfl(rec.x, idx, 64);
            float w = __int_as_float(__shfl(rec.y, idx, 64));
            float4 u = f4[(size_t)s * 32 + hl];
            if (j & 1) {
                a1.x += w * u.x; a1.y += w * u.y; a1.z += w * u.z; a1.w += w * u.w;
            } else {
                a0.x += w * u.x; a0.y += w * u.y; a0.z += w * u.z; a0.w += w * u.w;
            }
        }
    }
    // remainder: 2 edges per step (half 1 dups last record with w=0 if odd)
    for (; e < cnt; e += 2) {
        int j = e + half;
        int jc = (j < cnt) ? j : e;          // clamp to a valid record
        int2 p = csr[start + jc];
        float w = (j < cnt) ? __int_as_float(p.y) : 0.f;
        float4 u = f4[(size_t)p.x * 32 + hl];
        a0.x += w * u.x; a0.y += w * u.y; a0.z += w * u.z; a0.w += w * u.w;
    }

    float4 acc = make_float4(a0.x + a1.x, a0.y + a1.y, a0.z + a1.z, a0.w + a1.w);
    // combine halves
    acc.x += __shfl_xor(acc.x, 32, 64);
    acc.y += __shfl_xor(acc.y, 32, 64);
    acc.z += __shfl_xor(acc.z, 32, 64);
    acc.w += __shfl_xor(acc.w, 32, 64);

    float4 b = reinterpret_cast<const float4*>(bias)[hl];
    acc.x += b.x; acc.y += b.y; acc.z += b.z; acc.w += b.w;
    if (relu) {
        acc.x = fmaxf(acc.x, 0.f);
        acc.y = fmaxf(acc.y, 0.f);
        acc.z = fmaxf(acc.z, 0.f);
        acc.w = fmaxf(acc.w, 0.f);
    }
    if (do_pool) {
        if (half == 0) {
            int g = batch[node];
            atomicAdd(&gsum[g * DHID + 4 * hl + 0], acc.x);
            atomicAdd(&gsum[g * DHID + 4 * hl + 1], acc.y);
            atomicAdd(&gsum[g * DHID + 4 * hl + 2], acc.z);
            atomicAdd(&gsum[g * DHID + 4 * hl + 3], acc.w);
        }
    } else {
        if (half == 0)
            reinterpret_cast<float4*>(out)[(size_t)node * 32 + hl] = acc;
    }
}

// ---------------- head: mean + 128x10 + log_softmax ----------------
__global__ __launch_bounds__(128) void k_head(const float* __restrict__ gsum,
                                              const int* __restrict__ batch,
                                              const float* __restrict__ Wl,
                                              const float* __restrict__ bl,
                                              float* __restrict__ out) {
    __shared__ float pooled[128];
    __shared__ float logits[DOUT];
    int g = blockIdx.x;
    int t = threadIdx.x;
    int lo = 0, hi = NN;
    while (lo < hi) {
        int m = (lo + hi) >> 1;
        if (batch[m] < g) lo = m + 1;
        else hi = m;
    }
    int a = lo, b = NN;
    while (a < b) {
        int m = (a + b) >> 1;
        if (batch[m] < g + 1) a = m + 1;
        else b = m;
    }
    int cnt = a - lo;
    pooled[t] = gsum[g * DHID + t] / (float)max(cnt, 1);
    __syncthreads();
    if (t < DOUT) {
        float acc = bl[t];
        for (int k = 0; k < 128; k++) acc += pooled[k] * Wl[k * DOUT + t];
        logits[t] = acc;
    }
    __syncthreads();
    if (t < DOUT) {
        float m = -1e30f;
        for (int j = 0; j < DOUT; j++) m = fmaxf(m, logits[j]);
        float se = 0.f;
        for (int j = 0; j < DOUT; j++) se += expf(logits[j] - m);
        out[g * DOUT + t] = logits[t] - m - logf(se);
    }
}

// ---------------- launch ----------------
extern "C" void kernel_launch(void* const* d_in, const int* in_sizes, int n_in,
                              void* d_out, int out_size, void* d_ws, size_t ws_size,
                              hipStream_t stream) {
    const float* x  = (const float*)d_in[0];
    const int*   ei = (const int*)d_in[1];
    const int* batch = (const int*)d_in[2];
    const float* W1 = (const float*)d_in[3];
    const float* b1 = (const float*)d_in[4];
    const float* W2 = (const float*)d_in[5];
    const float* b2 = (const float*)d_in[6];
    const float* W3 = (const float*)d_in[7];
    const float* b3 = (const float*)d_in[8];
    const float* Wl = (const float*)d_in[9];
    const float* bl = (const float*)d_in[10];
    float* out = (float*)d_out;

    const int* src = ei;
    const int* dst = ei + NE;

    char* ws = (char*)d_ws;
    size_t off = 0;
    auto alloc = [&](size_t bytes) {
        void* p = ws + off;
        off += (bytes + 255) / 256 * 256;
        return p;
    };
    int*   deg     = (int*)alloc(NN * 4);
    int*   cursor  = (int*)alloc(NN * 4);
    float* dinv    = (float*)alloc(NN * 4);
    int*   offs    = (int*)alloc(NN * 4);
    int*   bsum    = (int*)alloc(1024);
    float* gsum    = (float*)alloc(NGR * DHID * 4);
    int2*  csr     = (int2*)alloc((size_t)NE * 8);
    float* bufA    = (float*)alloc((size_t)NN * 128 * 4);
    float* bufB    = (float*)alloc((size_t)NN * 128 * 4);

    int nb = (NN + 255) / 256;  // 196
    k_init<<<nb, 256, 0, stream>>>(deg, cursor, gsum);
    k_count<<<NE / 256, 256, 0, stream>>>(dst, deg);
    k_scanA<<<nb, 256, 0, stream>>>(deg, dinv, bsum);
    k_scanB<<<1, 256, 0, stream>>>(bsum, nb);
    k_scanC<<<nb, 256, 0, stream>>>(deg, bsum, offs);
    k_fill<<<NE / 256, 256, 0, stream>>>(src, dst, offs, cursor, dinv, csr);

    int gB = (NN + 63) / 64;  // 782
    k_gemm<<<gB, 256, 0, stream>>>(x, W1, bufA);
    k_agg<<<NN / 4, 256, 0, stream>>>(bufA, csr, offs, deg, dinv, b1, bufB, 1,
                                      batch, gsum, 0);
    k_gemm<<<gB, 256, 0, stream>>>(bufB, W2, bufA);
    k_agg<<<NN / 4, 256, 0, stream>>>(bufA, csr, offs, deg, dinv, b2, bufB, 1,
                                      batch, gsum, 0);
    k_gemm<<<gB, 256, 0, stream>>>(bufB, W3, bufA);
    k_agg<<<NN / 4, 256, 0, stream>>>(bufA, csr, offs, deg, dinv, b3, bufB, 0,
                                      batch, gsum, 1);
    k_head<<<NGR, 128, 0, stream>>>(gsum, batch, Wl, bl, out);
}

// Round 7
// 483.595 us; speedup vs baseline: 1.1954x; 1.1954x over previous
//
#include <hip/hip_runtime.h>

#define NN 50000      // nodes
#define NE 800000     // edges
#define DHID 128
#define NGR 128       // graphs
#define DOUT 10

__device__ __forceinline__ unsigned short f2bf(float f) {
    unsigned u = __float_as_uint(f);
    unsigned r = (u + 0x7FFFu + ((u >> 16) & 1u)) >> 16;   // RNE
    return (unsigned short)r;
}
__device__ __forceinline__ float bf_lo(unsigned int u) {   // element 2k
    return __uint_as_float(u << 16);
}
__device__ __forceinline__ float bf_hi(unsigned int u) {   // element 2k+1
    return __uint_as_float(u & 0xffff0000u);
}

// ---------------- CSR build ----------------

__global__ void k_init(int* deg, int* cursor, float* gsum) {
    int i = blockIdx.x * blockDim.x + threadIdx.x;
    if (i < NN) { deg[i] = 1; cursor[i] = 0; }   // 1 = self loop
    if (i < NGR * DHID) gsum[i] = 0.f;
}

__global__ void k_count(const int* __restrict__ dst, int* __restrict__ deg) {
    int e = blockIdx.x * blockDim.x + threadIdx.x;
    if (e < NE) atomicAdd(&deg[dst[e]], 1);
}

// capacity per node = (deg-1) padded up to multiple of 8
__device__ __forceinline__ int padcap(int cnt) { return ((cnt + 7) >> 3) << 3; }

// per-256-chunk sums of cap, plus dinv
__global__ void k_scanA(const int* __restrict__ deg, float* __restrict__ dinv,
                        int* __restrict__ bsum) {
    __shared__ int sm[256];
    int t = threadIdx.x;
    int i = blockIdx.x * 256 + t;
    int d = (i < NN) ? deg[i] : 1;
    if (i < NN) dinv[i] = rsqrtf((float)d);
    sm[t] = padcap(d - 1);
    __syncthreads();
    for (int o = 128; o > 0; o >>= 1) {
        if (t < o) sm[t] += sm[t + o];
        __syncthreads();
    }
    if (t == 0) bsum[blockIdx.x] = sm[0];
}

// exclusive scan of block sums (nb <= 256) in a single block
__global__ void k_scanB(int* bsum, int nb) {
    __shared__ int sm[256];
    int t = threadIdx.x;
    int v = (t < nb) ? bsum[t] : 0;
    sm[t] = v;
    __syncthreads();
    for (int o = 1; o < 256; o <<= 1) {
        int x = (t >= o) ? sm[t - o] : 0;
        __syncthreads();
        sm[t] += x;
        __syncthreads();
    }
    if (t < nb) bsum[t] = sm[t] - v;  // exclusive
}

__global__ void k_scanC(const int* __restrict__ deg, const int* __restrict__ bsum,
                        int* __restrict__ offs) {
    __shared__ int sm[256];
    int t = threadIdx.x;
    int i = blockIdx.x * 256 + t;
    int c = (i < NN) ? padcap(deg[i] - 1) : 0;
    sm[t] = c;
    __syncthreads();
    for (int o = 1; o < 256; o <<= 1) {
        int x = (t >= o) ? sm[t - o] : 0;
        __syncthreads();
        sm[t] += x;
        __syncthreads();
    }
    if (i < NN) offs[i] = bsum[blockIdx.x] + sm[t] - c;  // exclusive within chunk
}

// packed CSR record: .x = src index, .y = f32 weight bits
__global__ void k_fill(const int* __restrict__ src, const int* __restrict__ dst,
                       const int* __restrict__ offs, int* __restrict__ cursor,
                       const float* __restrict__ dinv,
                       int2* __restrict__ csr) {
    int e = blockIdx.x * blockDim.x + threadIdx.x;
    if (e >= NE) return;
    int s = src[e], d = dst[e];
    int p = offs[d] + atomicAdd(&cursor[d], 1);
    csr[p] = make_int2(s, __float_as_int(dinv[s] * dinv[d]));
}

// fill pad slots [cnt, cap) with {src=0, w=0}: exact no-op contributions
__global__ void k_pad(const int* __restrict__ deg, const int* __restrict__ offs,
                      int2* __restrict__ csr) {
    int i = blockIdx.x * blockDim.x + threadIdx.x;
    if (i >= NN) return;
    int cnt = deg[i] - 1;
    int cap = padcap(cnt);
    int base = offs[i];
    for (int p = cnt; p < cap; p++) csr[base + p] = make_int2(0, 0);
}

// ---------------- GEMM: Cb[NN x 128](bf16) = X[NN x 128](f32) * W[128 x 128] --
// 64-row block tile, full 128 cols. 256 threads = 16x16, 4x8 micro-tile.
__global__ __launch_bounds__(256) void k_gemm(const float* __restrict__ X,
                                              const float* __restrict__ W,
                                              unsigned short* __restrict__ Cb) {
    __shared__ float Xs[16][68];   // [k][row], padded
    __shared__ float Ws[16][128];  // [k][col]
    int t = threadIdx.x;
    int tx = t & 15, ty = t >> 4;
    int rowBase = blockIdx.x * 64;

    float acc[4][8];
#pragma unroll
    for (int i = 0; i < 4; i++)
#pragma unroll
        for (int j = 0; j < 8; j++) acc[i][j] = 0.f;

    for (int kk = 0; kk < 128; kk += 16) {
        {
            int r = t >> 2, q = t & 3;
            int grow = rowBase + r;
            float4 v = make_float4(0.f, 0.f, 0.f, 0.f);
            if (grow < NN)
                v = *reinterpret_cast<const float4*>(&X[grow * 128 + kk + 4 * q]);
            Xs[4 * q + 0][r] = v.x;
            Xs[4 * q + 1][r] = v.y;
            Xs[4 * q + 2][r] = v.z;
            Xs[4 * q + 3][r] = v.w;
        }
#pragma unroll
        for (int rep = 0; rep < 2; rep++) {
            int idx = t + rep * 256;
            int k = idx >> 5, c4 = idx & 31;
            *reinterpret_cast<float4*>(&Ws[k][4 * c4]) =
                *reinterpret_cast<const float4*>(&W[(kk + k) * 128 + 4 * c4]);
        }
        __syncthreads();
#pragma unroll
        for (int k = 0; k < 16; k++) {
            float4 xv = *reinterpret_cast<const float4*>(&Xs[k][4 * ty]);
            float4 w0 = *reinterpret_cast<const float4*>(&Ws[k][8 * tx]);
            float4 w1 = *reinterpret_cast<const float4*>(&Ws[k][8 * tx + 4]);
            float xa[4] = {xv.x, xv.y, xv.z, xv.w};
            float wa[8] = {w0.x, w0.y, w0.z, w0.w, w1.x, w1.y, w1.z, w1.w};
#pragma unroll
            for (int i = 0; i < 4; i++)
#pragma unroll
                for (int j = 0; j < 8; j++) acc[i][j] += xa[i] * wa[j];
        }
        __syncthreads();
    }
#pragma unroll
    for (int i = 0; i < 4; i++) {
        int grow = rowBase + 4 * ty + i;
        if (grow < NN) {
            uint4 o;
            o.x = (unsigned)f2bf(acc[i][0]) | ((unsigned)f2bf(acc[i][1]) << 16);
            o.y = (unsigned)f2bf(acc[i][2]) | ((unsigned)f2bf(acc[i][3]) << 16);
            o.z = (unsigned)f2bf(acc[i][4]) | ((unsigned)f2bf(acc[i][5]) << 16);
            o.w = (unsigned)f2bf(acc[i][6]) | ((unsigned)f2bf(acc[i][7]) << 16);
            *reinterpret_cast<uint4*>(
                &reinterpret_cast<unsigned int*>(Cb)[(size_t)grow * 64 + 4 * tx]) = o;
        }
    }
}

// ---------------- Aggregation: out = A_norm @ feat (+bias, relu / pool) -------
// feat is bf16 [NN x 128]; one wave per node, lane holds 2 features (1 uint).
// CSR rows padded to multiple of 8: no remainder loop. csr stream is
// software-pipelined one batch ahead.
__global__ __launch_bounds__(256) void k_agg(const unsigned int* __restrict__ feat,
                                             const int2* __restrict__ csr,
                                             const int* __restrict__ offs,
                                             const int* __restrict__ deg,
                                             const float* __restrict__ dinv,
                                             const float* __restrict__ bias,
                                             float* __restrict__ out, int relu,
                                             const int* __restrict__ batch,
                                             float* __restrict__ gsum, int do_pool) {
    int wid = threadIdx.x >> 6;
    int lane = threadIdx.x & 63;
    int node = blockIdx.x * 4 + wid;
    if (node >= NN) return;
    float di = dinv[node];
    unsigned int v = feat[(size_t)node * 64 + lane];
    float w0 = di * di;
    float2 a0 = make_float2(w0 * bf_lo(v), w0 * bf_hi(v));
    float2 a1 = make_float2(0.f, 0.f);
    float2 a2 = make_float2(0.f, 0.f);
    float2 a3 = make_float2(0.f, 0.f);
    int start = offs[node];
    int cap = padcap(deg[node] - 1);

    if (cap > 0) {
        int2 p[8];
#pragma unroll
        for (int j = 0; j < 8; j++) p[j] = csr[start + j];
        for (int e = 0; e < cap; e += 8) {
            unsigned int u[8];
#pragma unroll
            for (int j = 0; j < 8; j++) u[j] = feat[(size_t)p[j].x * 64 + lane];
            int2 pn[8];
            if (e + 8 < cap) {
#pragma unroll
                for (int j = 0; j < 8; j++) pn[j] = csr[start + e + 8 + j];
            }
#pragma unroll
            for (int j = 0; j < 8; j++) {
                float w = __int_as_float(p[j].y);
                float ux = bf_lo(u[j]), uy = bf_hi(u[j]);
                if ((j & 3) == 0) { a0.x += w * ux; a0.y += w * uy; }
                if ((j & 3) == 1) { a1.x += w * ux; a1.y += w * uy; }
                if ((j & 3) == 2) { a2.x += w * ux; a2.y += w * uy; }
                if ((j & 3) == 3) { a3.x += w * ux; a3.y += w * uy; }
            }
            if (e + 8 < cap) {
#pragma unroll
                for (int j = 0; j < 8; j++) p[j] = pn[j];
            }
        }
    }

    float2 acc = make_float2(a0.x + a1.x + a2.x + a3.x, a0.y + a1.y + a2.y + a3.y);
    float2 b = reinterpret_cast<const float2*>(bias)[lane];
    acc.x += b.x;
    acc.y += b.y;
    if (relu) {
        acc.x = fmaxf(acc.x, 0.f);
        acc.y = fmaxf(acc.y, 0.f);
    }
    if (do_pool) {
        int g = batch[node];
        atomicAdd(&gsum[g * DHID + 2 * lane + 0], acc.x);
        atomicAdd(&gsum[g * DHID + 2 * lane + 1], acc.y);
    } else {
        reinterpret_cast<float2*>(out)[(size_t)node * 64 + lane] = acc;
    }
}

// ---------------- head: mean + 128x10 + log_softmax ----------------
__global__ __launch_bounds__(128) void k_head(const float* __restrict__ gsum,
                                              const int* __restrict__ batch,
                                              const float* __restrict__ Wl,
                                              const float* __restrict__ bl,
                                              float* __restrict__ out) {
    __shared__ float pooled[128];
    __shared__ float logits[DOUT];
    int g = blockIdx.x;
    int t = threadIdx.x;
    int lo = 0, hi = NN;
    while (lo < hi) {
        int m = (lo + hi) >> 1;
        if (batch[m] < g) lo = m + 1;
        else hi = m;
    }
    int a = lo, b = NN;
    while (a < b) {
        int m = (a + b) >> 1;
        if (batch[m] < g + 1) a = m + 1;
        else b = m;
    }
    int cnt = a - lo;
    pooled[t] = gsum[g * DHID + t] / (float)max(cnt, 1);
    __syncthreads();
    if (t < DOUT) {
        float acc = bl[t];
        for (int k = 0; k < 128; k++) acc += pooled[k] * Wl[k * DOUT + t];
        logits[t] = acc;
    }
    __syncthreads();
    if (t < DOUT) {
        float m = -1e30f;
        for (int j = 0; j < DOUT; j++) m = fmaxf(m, logits[j]);
        float se = 0.f;
        for (int j = 0; j < DOUT; j++) se += expf(logits[j] - m);
        out[g * DOUT + t] = logits[t] - m - logf(se);
    }
}

// ---------------- launch ----------------
extern "C" void kernel_launch(void* const* d_in, const int* in_sizes, int n_in,
                              void* d_out, int out_size, void* d_ws, size_t ws_size,
                              hipStream_t stream) {
    const float* x  = (const float*)d_in[0];
    const int*   ei = (const int*)d_in[1];
    const int* batch = (const int*)d_in[2];
    const float* W1 = (const float*)d_in[3];
    const float* b1 = (const float*)d_in[4];
    const float* W2 = (const float*)d_in[5];
    const float* b2 = (const float*)d_in[6];
    const float* W3 = (const float*)d_in[7];
    const float* b3 = (const float*)d_in[8];
    const float* Wl = (const float*)d_in[9];
    const float* bl = (const float*)d_in[10];
    float* out = (float*)d_out;

    const int* src = ei;
    const int* dst = ei + NE;

    char* ws = (char*)d_ws;
    size_t off = 0;
    auto alloc = [&](size_t bytes) {
        void* p = ws + off;
        off += (bytes + 255) / 256 * 256;
        return p;
    };
    int*   deg     = (int*)alloc(NN * 4);
    int*   cursor  = (int*)alloc(NN * 4);
    float* dinv    = (float*)alloc(NN * 4);
    int*   offs    = (int*)alloc(NN * 4);
    int*   bsum    = (int*)alloc(1024);
    float* gsum    = (float*)alloc(NGR * DHID * 4);
    int2*  csr     = (int2*)alloc((size_t)(NE + 8 * NN) * 8);  // padded capacity
    unsigned short* hb = (unsigned short*)alloc((size_t)NN * 128 * 2);  // bf16 feat
    float* A       = (float*)alloc((size_t)NN * 128 * 4);               // f32 feat

    int nb = (NN + 255) / 256;  // 196
    k_init<<<nb, 256, 0, stream>>>(deg, cursor, gsum);
    k_count<<<NE / 256, 256, 0, stream>>>(dst, deg);
    k_scanA<<<nb, 256, 0, stream>>>(deg, dinv, bsum);
    k_scanB<<<1, 256, 0, stream>>>(bsum, nb);
    k_scanC<<<nb, 256, 0, stream>>>(deg, bsum, offs);
    k_fill<<<NE / 256, 256, 0, stream>>>(src, dst, offs, cursor, dinv, csr);
    k_pad<<<nb, 256, 0, stream>>>(deg, offs, csr);

    int gB = (NN + 63) / 64;  // 782
    const unsigned int* hbu = (const unsigned int*)hb;
    k_gemm<<<gB, 256, 0, stream>>>(x, W1, hb);
    k_agg<<<NN / 4, 256, 0, stream>>>(hbu, csr, offs, deg, dinv, b1, A, 1,
                                      batch, gsum, 0);
    k_gemm<<<gB, 256, 0, stream>>>(A, W2, hb);
    k_agg<<<NN / 4, 256, 0, stream>>>(hbu, csr, offs, deg, dinv, b2, A, 1,
                                      batch, gsum, 0);
    k_gemm<<<gB, 256, 0, stream>>>(A, W3, hb);
    k_agg<<<NN / 4, 256, 0, stream>>>(hbu, csr, offs, deg, dinv, b3, A, 0,
                                      batch, gsum, 1);
    k_head<<<NGR, 128, 0, stream>>>(gsum, batch, Wl, bl, out);
}

// Round 8
// 456.731 us; speedup vs baseline: 1.2657x; 1.0588x over previous
//
#include <hip/hip_runtime.h>

#define NN 50000      // nodes
#define NE 800000     // edges
#define DHID 128
#define NGR 128       // graphs
#define DOUT 10
#define CSR_LDS_CAP 128   // records per wave staged in LDS (max deg ~50 here)

__device__ __forceinline__ unsigned short f2bf(float f) {
    unsigned u = __float_as_uint(f);
    unsigned r = (u + 0x7FFFu + ((u >> 16) & 1u)) >> 16;   // RNE
    return (unsigned short)r;
}
__device__ __forceinline__ float bf_lo(unsigned int u) {   // element 2k
    return __uint_as_float(u << 16);
}
__device__ __forceinline__ float bf_hi(unsigned int u) {   // element 2k+1
    return __uint_as_float(u & 0xffff0000u);
}

// capacity per node = (deg-1) padded up to multiple of 4
__device__ __forceinline__ int padcap(int cnt) { return ((cnt + 3) >> 2) << 2; }

// ---------------- CSR build ----------------

__global__ void k_init(int* deg, int* cursor, float* gsum) {
    int i = blockIdx.x * blockDim.x + threadIdx.x;
    if (i < NN) { deg[i] = 1; cursor[i] = 0; }   // 1 = self loop
    if (i < NGR * DHID) gsum[i] = 0.f;
}

__global__ void k_count(const int* __restrict__ dst, int* __restrict__ deg) {
    int e = blockIdx.x * blockDim.x + threadIdx.x;
    if (e < NE) atomicAdd(&deg[dst[e]], 1);
}

// per-256-chunk sums of cap, plus dinv
__global__ void k_scanA(const int* __restrict__ deg, float* __restrict__ dinv,
                        int* __restrict__ bsum) {
    __shared__ int sm[256];
    int t = threadIdx.x;
    int i = blockIdx.x * 256 + t;
    int d = (i < NN) ? deg[i] : 1;
    if (i < NN) dinv[i] = rsqrtf((float)d);
    sm[t] = padcap(d - 1);
    __syncthreads();
    for (int o = 128; o > 0; o >>= 1) {
        if (t < o) sm[t] += sm[t + o];
        __syncthreads();
    }
    if (t == 0) bsum[blockIdx.x] = sm[0];
}

// exclusive scan of block sums (nb <= 256) in a single block
__global__ void k_scanB(int* bsum, int nb) {
    __shared__ int sm[256];
    int t = threadIdx.x;
    int v = (t < nb) ? bsum[t] : 0;
    sm[t] = v;
    __syncthreads();
    for (int o = 1; o < 256; o <<= 1) {
        int x = (t >= o) ? sm[t - o] : 0;
        __syncthreads();
        sm[t] += x;
        __syncthreads();
    }
    if (t < nb) bsum[t] = sm[t] - v;  // exclusive
}

__global__ void k_scanC(const int* __restrict__ deg, const int* __restrict__ bsum,
                        int* __restrict__ offs) {
    __shared__ int sm[256];
    int t = threadIdx.x;
    int i = blockIdx.x * 256 + t;
    int c = (i < NN) ? padcap(deg[i] - 1) : 0;
    sm[t] = c;
    __syncthreads();
    for (int o = 1; o < 256; o <<= 1) {
        int x = (t >= o) ? sm[t - o] : 0;
        __syncthreads();
        sm[t] += x;
        __syncthreads();
    }
    if (i < NN) offs[i] = bsum[blockIdx.x] + sm[t] - c;  // exclusive within chunk
}

// packed CSR record: .x = src index, .y = f32 weight bits
__global__ void k_fill(const int* __restrict__ src, const int* __restrict__ dst,
                       const int* __restrict__ offs, int* __restrict__ cursor,
                       const float* __restrict__ dinv,
                       int2* __restrict__ csr) {
    int e = blockIdx.x * blockDim.x + threadIdx.x;
    if (e >= NE) return;
    int s = src[e], d = dst[e];
    int p = offs[d] + atomicAdd(&cursor[d], 1);
    csr[p] = make_int2(s, __float_as_int(dinv[s] * dinv[d]));
}

// fill pad slots [cnt, cap) with {src=0, w=0}: exact no-op contributions
__global__ void k_pad(const int* __restrict__ deg, const int* __restrict__ offs,
                      int2* __restrict__ csr) {
    int i = blockIdx.x * blockDim.x + threadIdx.x;
    if (i >= NN) return;
    int cnt = deg[i] - 1;
    int cap = padcap(cnt);
    int base = offs[i];
    for (int p = cnt; p < cap; p++) csr[base + p] = make_int2(0, 0);
}

// ---------------- GEMM: Cb[NN x 128](bf16) = X[NN x 128](f32) * W[128 x 128] --
__global__ __launch_bounds__(256) void k_gemm(const float* __restrict__ X,
                                              const float* __restrict__ W,
                                              unsigned short* __restrict__ Cb) {
    __shared__ float Xs[16][68];   // [k][row], padded
    __shared__ float Ws[16][128];  // [k][col]
    int t = threadIdx.x;
    int tx = t & 15, ty = t >> 4;
    int rowBase = blockIdx.x * 64;

    float acc[4][8];
#pragma unroll
    for (int i = 0; i < 4; i++)
#pragma unroll
        for (int j = 0; j < 8; j++) acc[i][j] = 0.f;

    for (int kk = 0; kk < 128; kk += 16) {
        {
            int r = t >> 2, q = t & 3;
            int grow = rowBase + r;
            float4 v = make_float4(0.f, 0.f, 0.f, 0.f);
            if (grow < NN)
                v = *reinterpret_cast<const float4*>(&X[grow * 128 + kk + 4 * q]);
            Xs[4 * q + 0][r] = v.x;
            Xs[4 * q + 1][r] = v.y;
            Xs[4 * q + 2][r] = v.z;
            Xs[4 * q + 3][r] = v.w;
        }
#pragma unroll
        for (int rep = 0; rep < 2; rep++) {
            int idx = t + rep * 256;
            int k = idx >> 5, c4 = idx & 31;
            *reinterpret_cast<float4*>(&Ws[k][4 * c4]) =
                *reinterpret_cast<const float4*>(&W[(kk + k) * 128 + 4 * c4]);
        }
        __syncthreads();
#pragma unroll
        for (int k = 0; k < 16; k++) {
            float4 xv = *reinterpret_cast<const float4*>(&Xs[k][4 * ty]);
            float4 w0 = *reinterpret_cast<const float4*>(&Ws[k][8 * tx]);
            float4 w1 = *reinterpret_cast<const float4*>(&Ws[k][8 * tx + 4]);
            float xa[4] = {xv.x, xv.y, xv.z, xv.w};
            float wa[8] = {w0.x, w0.y, w0.z, w0.w, w1.x, w1.y, w1.z, w1.w};
#pragma unroll
            for (int i = 0; i < 4; i++)
#pragma unroll
                for (int j = 0; j < 8; j++) acc[i][j] += xa[i] * wa[j];
        }
        __syncthreads();
    }
#pragma unroll
    for (int i = 0; i < 4; i++) {
        int grow = rowBase + 4 * ty + i;
        if (grow < NN) {
            uint4 o;
            o.x = (unsigned)f2bf(acc[i][0]) | ((unsigned)f2bf(acc[i][1]) << 16);
            o.y = (unsigned)f2bf(acc[i][2]) | ((unsigned)f2bf(acc[i][3]) << 16);
            o.z = (unsigned)f2bf(acc[i][4]) | ((unsigned)f2bf(acc[i][5]) << 16);
            o.w = (unsigned)f2bf(acc[i][6]) | ((unsigned)f2bf(acc[i][7]) << 16);
            *reinterpret_cast<uint4*>(
                &reinterpret_cast<unsigned int*>(Cb)[(size_t)grow * 64 + 4 * tx]) = o;
        }
    }
}

// ---------------- Aggregation: out = A_norm @ feat (+bias, relu / pool) -------
// feat bf16 [NN x 128]; one wave per node, lane holds 2 features (1 uint).
// csr row staged through LDS via one coalesced per-lane load (8 lines per 64
// records instead of 1 line-touch per record). Rows padded to multiple of 4.
__global__ __launch_bounds__(256) void k_agg(const unsigned int* __restrict__ feat,
                                             const int2* __restrict__ csr,
                                             const int* __restrict__ offs,
                                             const int* __restrict__ deg,
                                             const float* __restrict__ dinv,
                                             const float* __restrict__ bias,
                                             float* __restrict__ out, int relu,
                                             const int* __restrict__ batch,
                                             float* __restrict__ gsum, int do_pool) {
    __shared__ int2 smCsr[4][CSR_LDS_CAP];
    int wid = threadIdx.x >> 6;
    int lane = threadIdx.x & 63;
    int node = blockIdx.x * 4 + wid;
    if (node >= NN) return;
    float di = dinv[node];
    unsigned int v = feat[(size_t)node * 64 + lane];
    float w0 = di * di;
    float2 a0 = make_float2(w0 * bf_lo(v), w0 * bf_hi(v));
    float2 a1 = make_float2(0.f, 0.f);
    float2 a2 = make_float2(0.f, 0.f);
    float2 a3 = make_float2(0.f, 0.f);
    int start = offs[node];
    int cap = padcap(deg[node] - 1);
    int capL = min(cap, CSR_LDS_CAP);

    // stage csr row into LDS, coalesced (wave-private region, no barrier needed)
    for (int i = lane; i < capL; i += 64) smCsr[wid][i] = csr[start + i];

    int e = 0;
    for (; e + 8 <= capL; e += 8) {
        int2 p[8];
#pragma unroll
        for (int j = 0; j < 8; j++) p[j] = smCsr[wid][e + j];
        unsigned int u[8];
#pragma unroll
        for (int j = 0; j < 8; j++) u[j] = feat[(size_t)p[j].x * 64 + lane];
#pragma unroll
        for (int j = 0; j < 8; j++) {
            float w = __int_as_float(p[j].y);
            float ux = bf_lo(u[j]), uy = bf_hi(u[j]);
            if ((j & 3) == 0) { a0.x += w * ux; a0.y += w * uy; }
            if ((j & 3) == 1) { a1.x += w * ux; a1.y += w * uy; }
            if ((j & 3) == 2) { a2.x += w * ux; a2.y += w * uy; }
            if ((j & 3) == 3) { a3.x += w * ux; a3.y += w * uy; }
        }
    }
    if (e < capL) {  // exactly 4 remain (cap is a multiple of 4)
        int2 p[4];
#pragma unroll
        for (int j = 0; j < 4; j++) p[j] = smCsr[wid][e + j];
        unsigned int u[4];
#pragma unroll
        for (int j = 0; j < 4; j++) u[j] = feat[(size_t)p[j].x * 64 + lane];
#pragma unroll
        for (int j = 0; j < 4; j++) {
            float w = __int_as_float(p[j].y);
            float ux = bf_lo(u[j]), uy = bf_hi(u[j]);
            if (j == 0) { a0.x += w * ux; a0.y += w * uy; }
            if (j == 1) { a1.x += w * ux; a1.y += w * uy; }
            if (j == 2) { a2.x += w * ux; a2.y += w * uy; }
            if (j == 3) { a3.x += w * ux; a3.y += w * uy; }
        }
    }
    // overflow beyond LDS capacity (deg > ~129; never for this data, kept safe)
    for (int q = capL; q < cap; q += 4) {
        int2 p[4];
#pragma unroll
        for (int j = 0; j < 4; j++) p[j] = csr[start + q + j];
#pragma unroll
        for (int j = 0; j < 4; j++) {
            float w = __int_as_float(p[j].y);
            unsigned int u = feat[(size_t)p[j].x * 64 + lane];
            a0.x += w * bf_lo(u);
            a0.y += w * bf_hi(u);
        }
    }

    float2 acc = make_float2(a0.x + a1.x + a2.x + a3.x, a0.y + a1.y + a2.y + a3.y);
    float2 b = reinterpret_cast<const float2*>(bias)[lane];
    acc.x += b.x;
    acc.y += b.y;
    if (relu) {
        acc.x = fmaxf(acc.x, 0.f);
        acc.y = fmaxf(acc.y, 0.f);
    }
    if (do_pool) {
        int g = batch[node];
        atomicAdd(&gsum[g * DHID + 2 * lane + 0], acc.x);
        atomicAdd(&gsum[g * DHID + 2 * lane + 1], acc.y);
    } else {
        reinterpret_cast<float2*>(out)[(size_t)node * 64 + lane] = acc;
    }
}

// ---------------- head: mean + 128x10 + log_softmax ----------------
__global__ __launch_bounds__(128) void k_head(const float* __restrict__ gsum,
                                              const int* __restrict__ batch,
                                              const float* __restrict__ Wl,
                                              const float* __restrict__ bl,
                                              float* __restrict__ out) {
    __shared__ float pooled[128];
    __shared__ float logits[DOUT];
    int g = blockIdx.x;
    int t = threadIdx.x;
    int lo = 0, hi = NN;
    while (lo < hi) {
        int m = (lo + hi) >> 1;
        if (batch[m] < g) lo = m + 1;
        else hi = m;
    }
    int a = lo, b = NN;
    while (a < b) {
        int m = (a + b) >> 1;
        if (batch[m] < g + 1) a = m + 1;
        else b = m;
    }
    int cnt = a - lo;
    pooled[t] = gsum[g * DHID + t] / (float)max(cnt, 1);
    __syncthreads();
    if (t < DOUT) {
        float acc = bl[t];
        for (int k = 0; k < 128; k++) acc += pooled[k] * Wl[k * DOUT + t];
        logits[t] = acc;
    }
    __syncthreads();
    if (t < DOUT) {
        float m = -1e30f;
        for (int j = 0; j < DOUT; j++) m = fmaxf(m, logits[j]);
        float se = 0.f;
        for (int j = 0; j < DOUT; j++) se += expf(logits[j] - m);
        out[g * DOUT + t] = logits[t] - m - logf(se);
    }
}

// ---------------- launch ----------------
extern "C" void kernel_launch(void* const* d_in, const int* in_sizes, int n_in,
                              void* d_out, int out_size, void* d_ws, size_t ws_size,
                              hipStream_t stream) {
    const float* x  = (const float*)d_in[0];
    const int*   ei = (const int*)d_in[1];
    const int* batch = (const int*)d_in[2];
    const float* W1 = (const float*)d_in[3];
    const float* b1 = (const float*)d_in[4];
    const float* W2 = (const float*)d_in[5];
    const float* b2 = (const float*)d_in[6];
    const float* W3 = (const float*)d_in[7];
    const float* b3 = (const float*)d_in[8];
    const float* Wl = (const float*)d_in[9];
    const float* bl = (const float*)d_in[10];
    float* out = (float*)d_out;

    const int* src = ei;
    const int* dst = ei + NE;

    char* ws = (char*)d_ws;
    size_t off = 0;
    auto alloc = [&](size_t bytes) {
        void* p = ws + off;
        off += (bytes + 255) / 256 * 256;
        return p;
    };
    int*   deg     = (int*)alloc(NN * 4);
    int*   cursor  = (int*)alloc(NN * 4);
    float* dinv    = (float*)alloc(NN * 4);
    int*   offs    = (int*)alloc(NN * 4);
    int*   bsum    = (int*)alloc(1024);
    float* gsum    = (float*)alloc(NGR * DHID * 4);
    int2*  csr     = (int2*)alloc((size_t)(NE + 4 * NN) * 8);  // padded capacity
    unsigned short* hb = (unsigned short*)alloc((size_t)NN * 128 * 2);  // bf16 feat
    float* A       = (float*)alloc((size_t)NN * 128 * 4);               // f32 feat

    int nb = (NN + 255) / 256;  // 196
    k_init<<<nb, 256, 0, stream>>>(deg, cursor, gsum);
    k_count<<<NE / 256, 256, 0, stream>>>(dst, deg);
    k_scanA<<<nb, 256, 0, stream>>>(deg, dinv, bsum);
    k_scanB<<<1, 256, 0, stream>>>(bsum, nb);
    k_scanC<<<nb, 256, 0, stream>>>(deg, bsum, offs);
    k_fill<<<NE / 256, 256, 0, stream>>>(src, dst, offs, cursor, dinv, csr);
    k_pad<<<nb, 256, 0, stream>>>(deg, offs, csr);

    int gB = (NN + 63) / 64;  // 782
    const unsigned int* hbu = (const unsigned int*)hb;
    k_gemm<<<gB, 256, 0, stream>>>(x, W1, hb);
    k_agg<<<NN / 4, 256, 0, stream>>>(hbu, csr, offs, deg, dinv, b1, A, 1,
                                      batch, gsum, 0);
    k_gemm<<<gB, 256, 0, stream>>>(A, W2, hb);
    k_agg<<<NN / 4, 256, 0, stream>>>(hbu, csr, offs, deg, dinv, b2, A, 1,
                                      batch, gsum, 0);
    k_gemm<<<gB, 256, 0, stream>>>(A, W3, hb);
    k_agg<<<NN / 4, 256, 0, stream>>>(hbu, csr, offs, deg, dinv, b3, A, 0,
                                      batch, gsum, 1);
    k_head<<<NGR, 128, 0, stream>>>(gsum, batch, Wl, bl, out);
}